// Round 1
// 276.965 us; speedup vs baseline: 1.0220x; 1.0220x over previous
//
#include <hip/hip_runtime.h>
#include <hip/hip_bf16.h>

// CQAttention: B=16, Lc=1024, Lq=512, d=512.  f32 I/O, bf16 MFMA GEMMs, f32 acc.
// Round 9: the four pure GEMMs (S, A, T, Bm) converted from reg-staged LDS to
// m97-style global_load_lds staging (linear [128][64] LDS, 4 waves, 64x64
// wave-tile, BK=64, 2 barriers/K-step).  k_mfma_S made a pure-bf16 GEMM by
// folding w3 into Q ( (C.w3)@Q^T == C@(Q.w3)^T ) and pre-converting C->bf16 and
// Q*w3->bf16 inside k_rowdots (which already reads all of C and Q).
// k_mfma_out (A assembled on the fly -> must reg-stage) unchanged this round.

#define NB 16
#define LC 1024
#define LQ 512
#define DM 512
#define D4 2048
#define NEGINF (-1e30f)
#define LDA32 40   // padded LDS k-stride for BK=32 tiles (k_mfma_out only)

typedef __bf16 v8bf __attribute__((ext_vector_type(8)));
typedef __bf16 v4bf __attribute__((ext_vector_type(4)));
typedef float  v4f  __attribute__((ext_vector_type(4)));

#define MFMA16 __builtin_amdgcn_mfma_f32_16x16x32_bf16

// direct global->LDS async copy, 16B per lane; LDS dest is wave-uniform base.
#define GLOAD16(gp, lp) __builtin_amdgcn_global_load_lds( \
    (const __attribute__((address_space(1))) void*)(gp), \
    (__attribute__((address_space(3))) void*)(lp), 16, 0, 0)

// ---- 8-wave tile setup (k_mfma_out): wave owns 64(m) x 32(n) ----
#define TILE_SETUP8 \
  const int t = threadIdx.x, lane = t & 63, wave = t >> 6; \
  const int wm = wave >> 2, wn = wave & 3, quad = lane >> 4, col = lane & 15; \
  const int sr = t >> 2;

#define ZERO_ACC8 \
  v4f acc[4][2]; \
  _Pragma("unroll") for (int x = 0; x < 4; ++x) \
  _Pragma("unroll") for (int y = 0; y < 2; ++y) \
  _Pragma("unroll") for (int r = 0; r < 4; ++r) acc[x][y][r] = 0.f;

#define FRAG_MMA8S(AL, BL, LDA, KO) do { \
  v8bf af_[4], bf_[2]; \
  _Pragma("unroll") for (int x = 0; x < 4; ++x) \
    af_[x] = *(const v8bf*)&AL[(wm * 64 + x * 16 + col) * LDA + KO + quad * 8]; \
  _Pragma("unroll") for (int y = 0; y < 2; ++y) \
    bf_[y] = *(const v8bf*)&BL[(wn * 32 + y * 16 + col) * LDA + KO + quad * 8]; \
  _Pragma("unroll") for (int x = 0; x < 4; ++x) \
  _Pragma("unroll") for (int y = 0; y < 2; ++y) \
    acc[x][y] = MFMA16(af_[x], bf_[y], acc[x][y], 0, 0, 0); \
} while (0)

// ---- 4-wave gload_lds GEMM core: 128x128 tile, wave-tile 64x64, BK=64 ----
#define GEMM_PROLOG \
  __shared__ __bf16 Al[128 * 64], Bl[128 * 64]; \
  int bx = blockIdx.x, by = blockIdx.y, bz = blockIdx.z; \
  xcd_remap(bx, by, bz); \
  const int b = bz, i0 = by * 128, n0 = bx * 128; \
  const int t = threadIdx.x, lane = t & 63, wave = t >> 6; \
  const int wm = wave >> 1, wn = wave & 1, quad = lane >> 4, col = lane & 15; \
  const int srow = wave * 32 + (lane >> 3), scol = (lane & 7) * 8; \
  v4f acc[4][4]; \
  _Pragma("unroll") for (int x = 0; x < 4; ++x) \
  _Pragma("unroll") for (int y = 0; y < 4; ++y) \
  _Pragma("unroll") for (int r = 0; r < 4; ++r) acc[x][y][r] = 0.f;

#define GEMM_KLOOP(Arow, Brow, LDGA, LDGB, KEXT) \
  for (int k0 = 0; k0 < (KEXT); k0 += 64) { \
    _Pragma("unroll") for (int u = 0; u < 4; ++u) { \
      GLOAD16(Arow + (size_t)(u * 8) * (LDGA) + k0, &Al[(wave * 32 + u * 8) * 64]); \
      GLOAD16(Brow + (size_t)(u * 8) * (LDGB) + k0, &Bl[(wave * 32 + u * 8) * 64]); \
    } \
    __syncthreads(); \
    _Pragma("unroll") for (int ko = 0; ko < 2; ++ko) { \
      v8bf af_[4], bf_[4]; \
      _Pragma("unroll") for (int x = 0; x < 4; ++x) \
        af_[x] = *(const v8bf*)&Al[(wm * 64 + x * 16 + col) * 64 + ko * 32 + quad * 8]; \
      _Pragma("unroll") for (int y = 0; y < 4; ++y) \
        bf_[y] = *(const v8bf*)&Bl[(wn * 64 + y * 16 + col) * 64 + ko * 32 + quad * 8]; \
      _Pragma("unroll") for (int x = 0; x < 4; ++x) \
      _Pragma("unroll") for (int y = 0; y < 4; ++y) \
        acc[x][y] = MFMA16(af_[x], bf_[y], acc[x][y], 0, 0, 0); \
    } \
    __syncthreads(); \
  }

// XCD-aware remap (L2 locality for n-tile siblings sharing an A-tile).
__device__ __forceinline__ void xcd_remap(int& bx, int& by, int& bz) {
  const int gx = gridDim.x, gy = gridDim.y, gz = gridDim.z;
  int flat = bx + gx * (by + gy * bz);
  int per = (gx * gy * gz) >> 3;
  int nw = (flat & 7) * per + (flat >> 3);
  bx = nw % gx;
  int r = nw / gx;
  by = r % gy;
  bz = r / gy;
}

__device__ __forceinline__ v8bf cvt8f(float4 a, float4 b) {
  v8bf h;
  h[0] = (__bf16)a.x; h[1] = (__bf16)a.y; h[2] = (__bf16)a.z; h[3] = (__bf16)a.w;
  h[4] = (__bf16)b.x; h[5] = (__bf16)b.y; h[6] = (__bf16)b.z; h[7] = (__bf16)b.w;
  return h;
}

// -------- K1: cw1[b,i] = C.w1, qw2[b,j] = Q.w2; also emits Cbf = bf16(C) and
// -------- Qw3 = bf16(Q*w3) for the pure-bf16 k_mfma_S (zero extra reads). ----
__global__ void k_rowdots(const float* __restrict__ C, const float* __restrict__ Q,
                          const float* __restrict__ w,
                          float* __restrict__ cw1, float* __restrict__ qw2,
                          __bf16* __restrict__ Cbf, __bf16* __restrict__ Qw3) {
  const int wid = threadIdx.x >> 6, lane = threadIdx.x & 63;
  const int row = blockIdx.x * 4 + wid;
  const bool isC = row < NB * LC;
  const int lr = isC ? row : row - NB * LC;
  const float* src = (isC ? C : Q) + (size_t)lr * DM;
  const float* wv  = isC ? w : (w + DM);
  const float* w3  = w + 2 * DM;
  __bf16* dst = (isC ? Cbf : Qw3) + (size_t)lr * DM;
  float v = 0.f;
#pragma unroll
  for (int s = 0; s < 2; ++s) {
    const int k = lane * 4 + s * 256;
    float4 f = *(const float4*)(src + k);
    float4 g = *(const float4*)(wv + k);
    v += f.x * g.x + f.y * g.y + f.z * g.z + f.w * g.w;
    v4bf h;
    if (isC) {
      h[0] = (__bf16)f.x; h[1] = (__bf16)f.y; h[2] = (__bf16)f.z; h[3] = (__bf16)f.w;
    } else {
      float4 s3 = *(const float4*)(w3 + k);
      h[0] = (__bf16)(f.x * s3.x); h[1] = (__bf16)(f.y * s3.y);
      h[2] = (__bf16)(f.z * s3.z); h[3] = (__bf16)(f.w * s3.w);
    }
    *(v4bf*)(dst + k) = h;
  }
#pragma unroll
  for (int off = 32; off; off >>= 1) v += __shfl_down(v, off, 64);
  if (lane == 0) {
    if (isC) cw1[row] = v;
    else     qw2[lr] = v;
  }
}

// ------- batched transpose: f32 in[R][Cd] -> bf16 outT[Cd][R] -------
__global__ void k_transpose(const float* __restrict__ in, __bf16* __restrict__ outT,
                            int R, int Cd) {
  __shared__ __bf16 tile[64][66];
  const int b = blockIdx.z;
  const int r0 = blockIdx.y * 64, c0 = blockIdx.x * 64;
  const int tr = threadIdx.x >> 6, tc = threadIdx.x & 63;
  const float* inb = in + (size_t)b * R * Cd;
  __bf16* outb = outT + (size_t)b * Cd * R;
  for (int r = tr; r < 64; r += 4)
    tile[r][tc] = (__bf16)inb[(size_t)(r0 + r) * Cd + c0 + tc];
  __syncthreads();
  for (int c = tr; c < 64; c += 4)
    outb[(size_t)(c0 + c) * R + r0 + tc] = tile[tc][c];
}

// ------- OW f32 -> bf16 (once; reused by all k_mfma_out blocks) -------
__global__ void k_owcvt(const float* __restrict__ OW, __bf16* __restrict__ OWb) {
  size_t i = ((size_t)blockIdx.x * 256 + threadIdx.x) * 4;
  float4 f = *(const float4*)(OW + i);
  v4bf h; h[0] = (__bf16)f.x; h[1] = (__bf16)f.y; h[2] = (__bf16)f.z; h[3] = (__bf16)f.w;
  *(v4bf*)(OWb + i) = h;
}

// ---------------- G1: S = cw1 + qw2 + Cbf @ Qw3^T  (gload_lds) ----------------
__global__ __launch_bounds__(256) void k_mfma_S(
    const __bf16* __restrict__ Cbf, const __bf16* __restrict__ Qw3,
    const float* __restrict__ cw1, const float* __restrict__ qw2,
    float* __restrict__ S) {
  GEMM_PROLOG
  const __bf16* Arow = Cbf + (size_t)b * LC * DM + (size_t)(i0 + srow) * DM + scol;
  const __bf16* Brow = Qw3 + (size_t)b * LQ * DM + (size_t)(n0 + srow) * DM + scol;
  GEMM_KLOOP(Arow, Brow, DM, DM, DM)
  float* Sb = S + (size_t)b * LC * LQ;
#pragma unroll
  for (int x = 0; x < 4; ++x) {
    const int mB = i0 + wm * 64 + x * 16 + quad * 4;
    float cv[4];
#pragma unroll
    for (int r = 0; r < 4; ++r) cv[r] = cw1[b * LC + mB + r];
#pragma unroll
    for (int y = 0; y < 4; ++y) {
      const int j = n0 + wn * 64 + y * 16 + col;
      const float qv = qw2[b * LQ + j];
#pragma unroll
      for (int r = 0; r < 4; ++r)
        Sb[(size_t)(mB + r) * LQ + j] = acc[x][y][r] + cv[r] + qv;
    }
  }
}

// ---- fused: row softmax (qmask) -> S1  AND  per-64i-chunk column stats ----
__global__ __launch_bounds__(1024) void k_softstat(
    const float* __restrict__ S, const float* __restrict__ qmask,
    const float* __restrict__ cmask, __bf16* __restrict__ S1,
    float2* __restrict__ pstat) {
  __shared__ float2 cst[16][LQ];
  const int b = blockIdx.y, ic = blockIdx.x;
  const int tid = threadIdx.x, wv = tid >> 6, lane = tid & 63;
  const float* qm  = qmask + b * LQ;
  const float* cm  = cmask + b * LC + ic * 64;
  const float* Sb  = S  + ((size_t)b * LC + ic * 64) * LQ;
  __bf16*      S1b = S1 + ((size_t)b * LC + ic * 64) * LQ;
  float colm[8], cols[8];
#pragma unroll
  for (int tt = 0; tt < 8; ++tt) { colm[tt] = -3e38f; cols[tt] = 0.f; }
  for (int it = 0; it < 4; ++it) {
    const int r = wv * 4 + it;
    const float cmv = cm[r];
    const float* Srow = Sb + (size_t)r * LQ;
    float sv[8], l1[8];
    float m = -3e38f;
#pragma unroll
    for (int tt = 0; tt < 8; ++tt) {
      int j = lane + 64 * tt;
      sv[tt] = Srow[j];
      float qv = qm[j];
      l1[tt] = qv * sv[tt] + (1.f - qv) * NEGINF;
      m = fmaxf(m, l1[tt]);
    }
#pragma unroll
    for (int off = 32; off; off >>= 1) m = fmaxf(m, __shfl_xor(m, off, 64));
    float e[8], s = 0.f;
#pragma unroll
    for (int tt = 0; tt < 8; ++tt) { e[tt] = __expf(l1[tt] - m); s += e[tt]; }
#pragma unroll
    for (int off = 32; off; off >>= 1) s += __shfl_xor(s, off, 64);
    const float inv = 1.f / s;
#pragma unroll
    for (int tt = 0; tt < 8; ++tt)
      S1b[(size_t)r * LQ + lane + 64 * tt] = (__bf16)(e[tt] * inv);
#pragma unroll
    for (int tt = 0; tt < 8; ++tt) {
      float l2 = cmv * sv[tt] + (1.f - cmv) * NEGINF;
      if (l2 > colm[tt]) { cols[tt] *= __expf(colm[tt] - l2); colm[tt] = l2; }
      cols[tt] += __expf(l2 - colm[tt]);
    }
  }
#pragma unroll
  for (int tt = 0; tt < 8; ++tt) cst[wv][lane + 64 * tt] = make_float2(colm[tt], cols[tt]);
  __syncthreads();
  if (tid < LQ) {
    float M = -3e38f, Sd = 0.f;
#pragma unroll
    for (int k = 0; k < 16; ++k) {
      float2 p = cst[k][tid];
      float nM = fmaxf(M, p.x);
      Sd = Sd * __expf(M - nM) + p.y * __expf(p.x - nM);
      M = nM;
    }
    pstat[((size_t)(b * 16 + ic) * LQ) + tid] = make_float2(M, Sd);
  }
}

// ---- col softmax phase 2: combine chunk stats, write TRANSPOSED S2T[j][i] ----
__global__ void k_colwrite(const float* __restrict__ S, const float* __restrict__ cmask,
                           const float2* __restrict__ pstat, __bf16* __restrict__ S2T) {
  __shared__ float Mf[64], If[64];
  __shared__ __bf16 tile[64][66];
  const int b = blockIdx.z, ic = blockIdx.y, j0 = blockIdx.x * 64;
  const int c = threadIdx.x & 63, ip = threadIdx.x >> 6;
  if (threadIdx.x < 64) {
    float M = -3e38f, Sd = 0.f;
#pragma unroll
    for (int k = 0; k < 16; ++k) {
      float2 p = pstat[((size_t)(b * 16 + k) * LQ) + j0 + threadIdx.x];
      float nM = fmaxf(M, p.x);
      Sd = Sd * __expf(M - nM) + p.y * __expf(p.x - nM);
      M = nM;
    }
    Mf[threadIdx.x] = M; If[threadIdx.x] = 1.f / Sd;
  }
  __syncthreads();
  const float M = Mf[c], inv = If[c];
  const float* Sb = S + ((size_t)b * LC + ic * 64) * LQ;
  const float* cm = cmask + b * LC + ic * 64;
  for (int r = ip; r < 64; r += 4) {
    float mk = cm[r];
    float logit = mk * Sb[(size_t)r * LQ + j0 + c] + (1.f - mk) * NEGINF;
    tile[r][c] = (__bf16)(__expf(logit - M) * inv);
  }
  __syncthreads();
  __bf16* S2Tb = S2T + ((size_t)b * LQ + j0) * LC + ic * 64;
  for (int jr = ip; jr < 64; jr += 4)
    S2Tb[(size_t)jr * LC + c] = tile[c][jr];
}

// ---------------- G2: A = S1 @ Q  (gload_lds) ----------------
__global__ __launch_bounds__(256) void k_mfma_A(
    const __bf16* __restrict__ S1, const __bf16* __restrict__ QT, __bf16* __restrict__ Aw) {
  GEMM_PROLOG
  const __bf16* Arow = S1 + (size_t)b * LC * LQ + (size_t)(i0 + srow) * LQ + scol;
  const __bf16* Brow = QT + (size_t)b * DM * LQ + (size_t)(n0 + srow) * LQ + scol;
  GEMM_KLOOP(Arow, Brow, LQ, LQ, LQ)
  __bf16* Ab = Aw + (size_t)b * LC * DM;
#pragma unroll
  for (int x = 0; x < 4; ++x) {
    const int mB = i0 + wm * 64 + x * 16 + quad * 4;
#pragma unroll
    for (int y = 0; y < 4; ++y) {
      const int n = n0 + wn * 64 + y * 16 + col;
#pragma unroll
      for (int r = 0; r < 4; ++r)
        Ab[(size_t)(mB + r) * DM + n] = (__bf16)acc[x][y][r];
    }
  }
}

// ------- G3: S2TC^T[n][j]  (A=S2T rows, B=CT rows; K=Lc; gload_lds) ----
__global__ __launch_bounds__(256) void k_mfma_T(
    const __bf16* __restrict__ S2T, const __bf16* __restrict__ CT, __bf16* __restrict__ S2TCT) {
  GEMM_PROLOG
  const int j0 = i0;
  const __bf16* Arow = S2T + (size_t)b * LQ * LC + (size_t)(j0 + srow) * LC + scol;
  const __bf16* Brow = CT  + (size_t)b * DM * LC + (size_t)(n0 + srow) * LC + scol;
  GEMM_KLOOP(Arow, Brow, LC, LC, LC)
#pragma unroll
  for (int x = 0; x < 4; ++x) {
    const int jB = j0 + wm * 64 + x * 16 + quad * 4;
#pragma unroll
    for (int y = 0; y < 4; ++y) {
      const int n = n0 + wn * 64 + y * 16 + col;
      v4bf h;
#pragma unroll
      for (int r = 0; r < 4; ++r) h[r] = (__bf16)acc[x][y][r];
      *(v4bf*)&S2TCT[((size_t)b * DM + n) * LQ + jB] = h;
    }
  }
}

// ---------------- G4: Bm = S1 @ S2TC  (gload_lds) ----------------
__global__ __launch_bounds__(256) void k_mfma_Bm(
    const __bf16* __restrict__ S1, const __bf16* __restrict__ S2TCT, __bf16* __restrict__ Bmw) {
  GEMM_PROLOG
  const __bf16* Arow = S1    + (size_t)b * LC * LQ + (size_t)(i0 + srow) * LQ + scol;
  const __bf16* Brow = S2TCT + (size_t)b * DM * LQ + (size_t)(n0 + srow) * LQ + scol;
  GEMM_KLOOP(Arow, Brow, LQ, LQ, LQ)
  __bf16* Bb = Bmw + (size_t)b * LC * DM;
#pragma unroll
  for (int x = 0; x < 4; ++x) {
    const int mB = i0 + wm * 64 + x * 16 + quad * 4;
#pragma unroll
    for (int y = 0; y < 4; ++y) {
      const int n = n0 + wn * 64 + y * 16 + col;
#pragma unroll
      for (int r = 0; r < 4; ++r)
        Bb[(size_t)(mB + r) * DM + n] = (__bf16)acc[x][y][r];
    }
  }
}

// -------- G5: out = [C, A, C*A, C*Bm] @ out_w^T + out_b  (1-pass 4-seg) ------
__global__ __launch_bounds__(512) void k_mfma_out(
    const float* __restrict__ C, const __bf16* __restrict__ Aw, const __bf16* __restrict__ Bmw,
    const __bf16* __restrict__ OWb, const float* __restrict__ ob, float* __restrict__ out) {
  __shared__ __bf16 Asg[4][128 * LDA32], Bsg[4][128 * LDA32];   // 80 KiB
  int bx = blockIdx.x, by = blockIdx.y, bz = blockIdx.z;
  xcd_remap(bx, by, bz);
  const int b = bz, i0 = by * 128, n0 = bx * 128;
  TILE_SETUP8
  const int skc = (t & 3) * 8;
  const float*  Cr = C   + (size_t)b * LC * DM + (size_t)(i0 + sr) * DM + skc;
  const __bf16* Ar = Aw  + (size_t)b * LC * DM + (size_t)(i0 + sr) * DM + skc;
  const __bf16* Br = Bmw + (size_t)b * LC * DM + (size_t)(i0 + sr) * DM + skc;
  const __bf16* Wr = OWb + (size_t)(n0 + sr) * D4 + skc;
  float4 pc0, pc1; v8bf pA, pB, pw[4];
  auto load = [&](int kl) {
    pc0 = *(const float4*)(Cr + kl); pc1 = *(const float4*)(Cr + kl + 4);
    pA = *(const v8bf*)(Ar + kl);
    pB = *(const v8bf*)(Br + kl);
#pragma unroll
    for (int s = 0; s < 4; ++s) pw[s] = *(const v8bf*)(Wr + s * DM + kl);
  };
  load(0);
  ZERO_ACC8
  for (int kl = 0; kl < DM; kl += 32) {
    float cf[8] = {pc0.x, pc0.y, pc0.z, pc0.w, pc1.x, pc1.y, pc1.z, pc1.w};
    v8bf hC, hCA, hCB;
#pragma unroll
    for (int e = 0; e < 8; ++e) {
      hC[e]  = (__bf16)cf[e];
      hCA[e] = (__bf16)(cf[e] * (float)pA[e]);
      hCB[e] = (__bf16)(cf[e] * (float)pB[e]);
    }
    const int off = sr * LDA32 + skc;
    *(v8bf*)&Asg[0][off] = hC;
    *(v8bf*)&Asg[1][off] = pA;
    *(v8bf*)&Asg[2][off] = hCA;
    *(v8bf*)&Asg[3][off] = hCB;
#pragma unroll
    for (int s = 0; s < 4; ++s) *(v8bf*)&Bsg[s][off] = pw[s];
    __syncthreads();
    int kn = kl + 32; if (kn >= DM) kn = 0;
    load(kn);                                 // prefetch next chunk
#pragma unroll
    for (int s = 0; s < 4; ++s) FRAG_MMA8S(Asg[s], Bsg[s], LDA32, 0);
    __syncthreads();
  }
  float* outb = out + (size_t)b * LC * DM;
#pragma unroll
  for (int x = 0; x < 4; ++x) {
    const int mB = i0 + wm * 64 + x * 16 + quad * 4;
#pragma unroll
    for (int y = 0; y < 2; ++y) {
      const int n = n0 + wn * 32 + y * 16 + col;
      const float bv = ob[n];
#pragma unroll
      for (int r = 0; r < 4; ++r)
        outb[(size_t)(mB + r) * DM + n] = acc[x][y][r] + bv;
    }
  }
}

extern "C" void kernel_launch(void* const* d_in, const int* in_sizes, int n_in,
                              void* d_out, int out_size, void* d_ws, size_t ws_size,
                              hipStream_t stream) {
  const float* C     = (const float*)d_in[0];
  const float* Q     = (const float*)d_in[1];
  const float* cmask = (const float*)d_in[2];
  const float* qmask = (const float*)d_in[3];
  const float* w     = (const float*)d_in[4];
  const float* out_w = (const float*)d_in[5];
  const float* out_b = (const float*)d_in[6];
  float* out = (float*)d_out;

  // ---- workspace carve (72 MiB + 128 KiB; validated). Aliased by lifetime:
  //  R[0,16Mi):   S.lo          -> Aw
  //  R[16,32Mi):  S.hi          -> CT -> Bmw
  //  +32Mi: Cbf (16Mi, rowdots->S)  -> S1 (16 Mi)
  //  +48Mi: Qw3 (8Mi, rowdots->S)   -> S2T (16 Mi) -> OWbf (2 Mi, after k_mfma_T)
  //  +64Mi: pstat(1Mi) -> QT(8Mi) -> S2TCT(8Mi)
  char* base = (char*)d_ws;
  float*  cw1   = (float*)base;
  float*  qw2   = (float*)(base + 65536);
  char*   R     = base + 131072;
  float*  S     = (float*)R;
  __bf16* Aw    = (__bf16*)R;
  __bf16* CT    = (__bf16*)(R + (16u << 20));
  __bf16* Bmw   = (__bf16*)(R + (16u << 20));
  __bf16* Cbf   = (__bf16*)(base + 131072 + (32u << 20));
  __bf16* S1    = (__bf16*)(base + 131072 + (32u << 20));
  __bf16* Qw3   = (__bf16*)(base + 131072 + (48u << 20));
  __bf16* S2T   = (__bf16*)(base + 131072 + (48u << 20));
  __bf16* OWbf  = S2T;   // 2 MiB, written after k_mfma_T consumes S2T
  char*   Z     = base + 131072 + (64u << 20);
  float2* pstat = (float2*)Z;
  __bf16* QT    = (__bf16*)Z;
  __bf16* S2TCT = (__bf16*)Z;
  (void)in_sizes; (void)n_in; (void)out_size; (void)ws_size;

  k_rowdots<<<(NB * LC + NB * LQ) / 4, 256, 0, stream>>>(C, Q, w, cw1, qw2, Cbf, Qw3);
  k_mfma_S<<<dim3(LQ / 128, LC / 128, NB), 256, 0, stream>>>(Cbf, Qw3, cw1, qw2, S);
  k_softstat<<<dim3(LC / 64, NB), 1024, 0, stream>>>(S, qmask, cmask, S1, pstat);
  k_colwrite<<<dim3(LQ / 64, LC / 64, NB), 256, 0, stream>>>(S, cmask, pstat, S2T);
  k_transpose<<<dim3(DM / 64, LQ / 64, NB), 256, 0, stream>>>(Q, QT, LQ, DM);
  k_transpose<<<dim3(DM / 64, LC / 64, NB), 256, 0, stream>>>(C, CT, LC, DM);
  k_mfma_A<<<dim3(DM / 128, LC / 128, NB), 256, 0, stream>>>(S1, QT, Aw);
  k_mfma_T<<<dim3(DM / 128, LQ / 128, NB), 256, 0, stream>>>(S2T, CT, S2TCT);
  k_owcvt<<<DM * D4 / 1024, 256, 0, stream>>>(out_w, OWbf);
  k_mfma_Bm<<<dim3(DM / 128, LC / 128, NB), 256, 0, stream>>>(S1, S2TCT, Bmw);
  k_mfma_out<<<dim3(DM / 128, LC / 128, NB), 512, 0, stream>>>(C, Aw, Bmw, OWbf, out_b, out);
}